// Round 4
// baseline (305.511 us; speedup 1.0000x reference)
//
#include <hip/hip_runtime.h>

#define N 96
#define NNN (N * N * N)
#define C_CH 32

// tile geometry: block 8x8x4 = 256 threads, each thread computes 2 voxels along w
// tile = 16(w) x 8(h) x 4(d); grid = 6 x 12 x 24 = 1728 blocks
#define TXD 8
#define TYD 8
#define TZD 4
#define VX 2
#define TW (TXD * VX)          // 16
#define TH TYD                 // 8
#define TD TZD                 // 4

// halo tile in LDS: 18 x 10 x 6, row padded to 19 (odd stride -> good bank spread)
#define HWS 19
#define HH 10
#define HD 6
#define PLANE (HWS * HH)       // 190
#define HTOT (PLANE * HD)      // 1140
#define NTH (TXD * TYD * TZD)  // 256
#define NR ((HTOT + NTH - 1) / NTH)  // 5 staging rounds
#define SMSZ (NR * NTH)        // 1280 (over-allocated so stores are unconditional)

__global__ __launch_bounds__(NTH, 4) void wincorr_kernel(
    const float* __restrict__ fixedp,
    const float* __restrict__ movingp,
    float* __restrict__ outp)
{
    __shared__ float sm[SMSZ];

    const int tx = threadIdx.x;   // 0..7  (w / 2)
    const int ty = threadIdx.y;   // 0..7  (h)
    const int tz = threadIdx.z;   // 0..3  (d)
    const int tid = tx + TXD * ty + TXD * TYD * tz;

    const int w0 = blockIdx.x * TW;
    const int h0 = blockIdx.y * TH;
    const int d0 = blockIdx.z * TD;

    // ---- channel-invariant staging source offsets ----
    // storage word a = tid + r*NTH maps to (z,y,x) with x-stride 1, row stride 19
    int off[NR];
    #pragma unroll
    for (int r = 0; r < NR; ++r) {
        const int a = tid + r * NTH;
        const int z   = a / PLANE;
        const int rm  = a - z * PLANE;
        const int y   = rm / HWS;
        const int x   = rm - y * HWS;
        const int sd = d0 - 1 + z;
        const int sh = h0 - 1 + y;
        const int sw = w0 - 1 + x;
        const bool ok = (a < HTOT) && (x < HWS - 1) &&
                        ((unsigned)sd < N) && ((unsigned)sh < N) && ((unsigned)sw < N);
        off[r] = ok ? ((sd * N + sh) * N + sw) : -1;
    }

    const int gw = w0 + VX * tx;
    const int fix_base = ((d0 + tz) * N + (h0 + ty)) * N + gw;
    const int lbase = tz * PLANE + ty * HWS + VX * tx;

    float acc[27][VX];
    #pragma unroll
    for (int s = 0; s < 27; ++s)
        #pragma unroll
        for (int v = 0; v < VX; ++v) acc[s][v] = 0.0f;

    // ---- prologue: prefetch channel 0 ----
    float st[NR];
    #pragma unroll
    for (int r = 0; r < NR; ++r)
        st[r] = (off[r] >= 0) ? movingp[off[r]] : 0.0f;
    float2 fnext = *(const float2*)&fixedp[fix_base];

    for (int c = 0; c < C_CH; ++c) {
        __syncthreads();   // previous iteration's LDS reads complete
        #pragma unroll
        for (int r = 0; r < NR; ++r)
            sm[tid + r * NTH] = st[r];
        __syncthreads();

        const float fv[VX] = {fnext.x, fnext.y};

        // prefetch next channel while computing this one (loads stay in flight)
        if (c + 1 < C_CH) {
            const float* mnext = movingp + (size_t)(c + 1) * NNN;
            #pragma unroll
            for (int r = 0; r < NR; ++r)
                st[r] = (off[r] >= 0) ? mnext[off[r]] : 0.0f;
            fnext = *(const float2*)&fixedp[(size_t)(c + 1) * NNN + fix_base];
        }

        // compute: 9 rows x 4-float sliding window, 27 taps x 2 voxels
        #pragma unroll
        for (int i = 0; i < 3; ++i) {
            #pragma unroll
            for (int j = 0; j < 3; ++j) {
                const float* row = &sm[lbase + i * PLANE + j * HWS];
                float wv[VX + 2];
                #pragma unroll
                for (int m = 0; m < VX + 2; ++m) wv[m] = row[m];
                #pragma unroll
                for (int k = 0; k < 3; ++k)
                    #pragma unroll
                    for (int v = 0; v < VX; ++v)
                        acc[(i * 3 + j) * 3 + k][v] += fv[v] * wv[v + k];
            }
        }
    }

    const float scale = 0.17677669529663687f; // 32^-0.5
    #pragma unroll
    for (int s = 0; s < 27; ++s) {
        float2 o;
        o.x = acc[s][0] * scale;
        o.y = acc[s][1] * scale;
        *(float2*)&outp[(size_t)s * NNN + fix_base] = o;
    }
}

extern "C" void kernel_launch(void* const* d_in, const int* in_sizes, int n_in,
                              void* d_out, int out_size, void* d_ws, size_t ws_size,
                              hipStream_t stream) {
    const float* fixedp  = (const float*)d_in[0];
    const float* movingp = (const float*)d_in[1];
    float* outp = (float*)d_out;

    dim3 block(TXD, TYD, TZD);                    // 8 x 8 x 4 = 256
    dim3 grid(N / TW, N / TH, N / TD);            // 6 x 12 x 24 = 1728
    wincorr_kernel<<<grid, block, 0, stream>>>(fixedp, movingp, outp);
}